// Round 1
// baseline (62.529 us; speedup 1.0000x reference)
//
#include <hip/hip_runtime.h>

#define B 4
#define P 1024
#define M 12
#define N 256
#define L 512
#define D 256
#define DC 256
#define FEA 1064          // 2*D + 20 + 20 + 2*DC
#define ROWS (B * P * M)  // 49152
#define NV 266            // FEA / 4 float4s per row

__device__ __forceinline__ int dis2idx(int u) {
    // DIS2IDX table: 0->0, else floor(log2(u)) + 1  (u in [0,512))
    return (u == 0) ? 0 : (32 - __clz(u));
}

__global__ __launch_bounds__(256) void decompose_kernel(
    const int* __restrict__ rel,    // [B,P,M,4]
    const int* __restrict__ pinfo,  // [B,N,6]
    const float* __restrict__ gf,   // [B,N,D]
    const float* __restrict__ cf,   // [B,L,DC]
    const float* __restrict__ dw,   // [20,20]
    const float* __restrict__ sw,   // [20,20]
    float* __restrict__ out)        // [ROWS*FEA] fea ++ [ROWS] mask
{
    const int row = blockIdx.x;            // (b*P + p)*M + m
    const int tid = threadIdx.x;
    const int b = row / (P * M);
    const int m = row % M;
    const int branch = m >> 2;             // 0,1,2 for the three _branch calls

    // sel = relation_path[b,p,m,0..3] (contiguous int4)
    const int4 sel = *reinterpret_cast<const int4*>(rel + (size_t)row * 4);

    // zero_mask = sum(sel) > 0 (indices nonneg)
    const float zf = ((sel.x + sel.y + sel.z + sel.w) > 0) ? 1.0f : 0.0f;

    // ga = 0 always; gb = 2 for branch 0, else 3
    const int ia = sel.x;
    const int ib = (branch == 0) ? sel.z : sel.w;
    const bool logical = (branch == 2);

    const int* pbase = pinfo + (size_t)b * N * 6;  // pos[n] = pbase[n*6]
    const int pos_ia = pbase[ia * 6];
    const int pos_ib = pbase[ib * 6];
    const int delta = pos_ia - pos_ib;
    const int u = delta & 511;                 // jnp.mod(delta, 512)
    const int d2 = dis2idx(u);
    const int idx = (delta < 0) ? (10 - d2) : (10 + d2);

    // context gather rows (token positions)
    const int s0 = pbase[sel.x * 6];
    const int s2 = pbase[sel.z * 6];
    int s1 = 0, s3 = 0;
    if (logical) { s1 = pbase[sel.y * 6]; s3 = pbase[sel.w * 6]; }

    const float4* gA  = reinterpret_cast<const float4*>(gf + ((size_t)b * N + ia) * D);
    const float4* gB  = reinterpret_cast<const float4*>(gf + ((size_t)b * N + ib) * D);
    const float4* dwr = reinterpret_cast<const float4*>(dw + idx * 20);
    const float4* swr = reinterpret_cast<const float4*>(sw + idx * 20);
    const float*  cb  = cf + (size_t)b * L * DC;
    const float4* c0  = reinterpret_cast<const float4*>(cb + (size_t)s0 * DC);
    const float4* c1  = reinterpret_cast<const float4*>(cb + (size_t)s1 * DC);
    const float4* c2  = reinterpret_cast<const float4*>(cb + (size_t)s2 * DC);
    const float4* c3  = reinterpret_cast<const float4*>(cb + (size_t)s3 * DC);

    float4* orow = reinterpret_cast<float4*>(out + (size_t)row * FEA);

    for (int j = tid; j < NV; j += 256) {
        float4 v;
        if (j < 64) {                       // rep: gf[b, ia]
            v = gA[j];
        } else if (j < 128) {               // rep: gf[b, ib]
            v = gB[j - 64];
        } else if (j < 133) {               // emb: dw[idx] (20 f32 = 5 float4)
            v = dwr[j - 128];
        } else if (j < 138) {               // semb: sw[idx]
            v = swr[j - 133];
        } else if (j < 202) {               // con first half
            const int k = j - 138;
            v = c0[k];
            if (logical) { const float4 w = c1[k]; v.x += w.x; v.y += w.y; v.z += w.z; v.w += w.w; }
        } else {                            // con second half
            const int k = j - 202;
            v = c2[k];
            if (logical) { const float4 w = c3[k]; v.x += w.x; v.y += w.y; v.z += w.z; v.w += w.w; }
        }
        v.x *= zf; v.y *= zf; v.z *= zf; v.w *= zf;
        orow[j] = v;
    }

    if (tid == 0) {
        // ret_mask = sum(sel > 0) > 0
        const bool rm = (sel.x > 0) || (sel.y > 0) || (sel.z > 0) || (sel.w > 0);
        out[(size_t)ROWS * FEA + row] = rm ? 1.0f : 0.0f;
    }
}

extern "C" void kernel_launch(void* const* d_in, const int* in_sizes, int n_in,
                              void* d_out, int out_size, void* d_ws, size_t ws_size,
                              hipStream_t stream) {
    const int*   rel   = (const int*)d_in[0];
    const int*   pinfo = (const int*)d_in[1];
    const float* gf    = (const float*)d_in[2];
    const float* cf    = (const float*)d_in[3];
    const float* dw    = (const float*)d_in[4];
    const float* sw    = (const float*)d_in[5];
    float* out = (float*)d_out;

    decompose_kernel<<<ROWS, 256, 0, stream>>>(rel, pinfo, gf, cf, dw, sw, out);
}

// Round 3
// 60.241 us; speedup vs baseline: 1.0380x; 1.0380x over previous
//
#include <hip/hip_runtime.h>

#define B 4
#define P 1024
#define M 12
#define N 256
#define L 512
#define D 256
#define DC 256
#define FEA 1064          // 2*D + 20 + 20 + 2*DC
#define ROWS (B * P * M)  // 49152
#define NV 266            // FEA / 4 float4s per row
#define NBLK 2048         // 8 blocks/CU * 256 CUs

typedef float f32x4 __attribute__((ext_vector_type(4)));

__device__ __forceinline__ int dis2idx(int u) {
    // DIS2IDX table: 0->0, else floor(log2(u)) + 1  (u in [0,512))
    return (u == 0) ? 0 : (32 - __clz(u));
}

__global__ __launch_bounds__(256) void decompose_kernel(
    const int* __restrict__ rel,    // [B,P,M,4]
    const int* __restrict__ pinfo,  // [B,N,6]
    const float* __restrict__ gf,   // [B,N,D]
    const float* __restrict__ cf,   // [B,L,DC]
    const float* __restrict__ dw,   // [20,20]
    const float* __restrict__ sw,   // [20,20]
    float* __restrict__ out)        // [ROWS*FEA] fea ++ [ROWS] mask
{
    const int lane  = threadIdx.x & 63;
    const int gwave = (blockIdx.x * 256 + threadIdx.x) >> 6;  // global wave id
    const int nwav  = NBLK * 4;

    for (int row = gwave; row < ROWS; row += nwav) {
        const int b = row / (P * M);
        const int m = row % M;
        const int branch = m >> 2;             // 0,1,2 for the three _branch calls

        // sel = relation_path[b,p,m,0..3] (contiguous int4) — wave-uniform
        const int4 sel = *reinterpret_cast<const int4*>(rel + (size_t)row * 4);

        // zero_mask = sum(sel) > 0 (indices nonneg)
        const float zf = ((sel.x + sel.y + sel.z + sel.w) > 0) ? 1.0f : 0.0f;

        // ga = 0 always; gb = 2 for branch 0, else 3
        const int ia = sel.x;
        const int ib = (branch == 0) ? sel.z : sel.w;
        const bool logical = (branch == 2);

        const int* pbase = pinfo + (size_t)b * N * 6;  // pos[n] = pbase[n*6]
        const int pos_ia = pbase[ia * 6];
        const int pos_ib = pbase[ib * 6];
        const int delta = pos_ia - pos_ib;
        const int u = delta & 511;                 // jnp.mod(delta, 512)
        const int d2 = dis2idx(u);
        const int idx = (delta < 0) ? (10 - d2) : (10 + d2);

        // context gather rows (token positions)
        const int s0 = pbase[sel.x * 6];
        const int s2 = pbase[sel.z * 6];
        int s1 = 0, s3 = 0;
        if (logical) { s1 = pbase[sel.y * 6]; s3 = pbase[sel.w * 6]; }

        const f32x4* gA  = reinterpret_cast<const f32x4*>(gf + ((size_t)b * N + ia) * D);
        const f32x4* gB  = reinterpret_cast<const f32x4*>(gf + ((size_t)b * N + ib) * D);
        const f32x4* dwr = reinterpret_cast<const f32x4*>(dw + idx * 20);
        const f32x4* swr = reinterpret_cast<const f32x4*>(sw + idx * 20);
        const float*  cb  = cf + (size_t)b * L * DC;
        const f32x4* c0  = reinterpret_cast<const f32x4*>(cb + (size_t)s0 * DC);
        const f32x4* c1  = reinterpret_cast<const f32x4*>(cb + (size_t)s1 * DC);
        const f32x4* c2  = reinterpret_cast<const f32x4*>(cb + (size_t)s2 * DC);
        const f32x4* c3  = reinterpret_cast<const f32x4*>(cb + (size_t)s3 * DC);

        f32x4* orow = reinterpret_cast<f32x4*>(out + (size_t)row * FEA);

        #pragma unroll
        for (int i = 0; i < 5; ++i) {
            const int j = lane + i * 64;
            if (j < NV) {
                f32x4 v;
                if (j < 64) {                       // rep: gf[b, ia]
                    v = gA[j];
                } else if (j < 128) {               // rep: gf[b, ib]
                    v = gB[j - 64];
                } else if (j < 133) {               // emb: dw[idx] (20 f32 = 5 float4)
                    v = dwr[j - 128];
                } else if (j < 138) {               // semb: sw[idx]
                    v = swr[j - 133];
                } else if (j < 202) {               // con first half
                    const int k = j - 138;
                    v = c0[k];
                    if (logical) v += c1[k];
                } else {                            // con second half
                    const int k = j - 202;
                    v = c2[k];
                    if (logical) v += c3[k];
                }
                v *= zf;
                __builtin_nontemporal_store(v, &orow[j]);
            }
        }

        if (lane == 0) {
            // ret_mask = sum(sel > 0) > 0
            const bool rm = (sel.x > 0) || (sel.y > 0) || (sel.z > 0) || (sel.w > 0);
            __builtin_nontemporal_store(rm ? 1.0f : 0.0f, &out[(size_t)ROWS * FEA + row]);
        }
    }
}

extern "C" void kernel_launch(void* const* d_in, const int* in_sizes, int n_in,
                              void* d_out, int out_size, void* d_ws, size_t ws_size,
                              hipStream_t stream) {
    const int*   rel   = (const int*)d_in[0];
    const int*   pinfo = (const int*)d_in[1];
    const float* gf    = (const float*)d_in[2];
    const float* cf    = (const float*)d_in[3];
    const float* dw    = (const float*)d_in[4];
    const float* sw    = (const float*)d_in[5];
    float* out = (float*)d_out;

    decompose_kernel<<<NBLK, 256, 0, stream>>>(rel, pinfo, gf, cf, dw, sw, out);
}

// Round 4
// 47.791 us; speedup vs baseline: 1.3084x; 1.2605x over previous
//
#include <hip/hip_runtime.h>

#define B 4
#define P 1024
#define M 12
#define N 256
#define L 512
#define D 256
#define DC 256
#define FEA 1064          // 2*D + 20 + 20 + 2*DC
#define ROWS (B * P * M)  // 49152
#define NBLK 2048         // persistent blocks for stream kernel

typedef float f32x4 __attribute__((ext_vector_type(4)));

// ---------------- setup: per-row descriptor + mask ----------------
__global__ __launch_bounds__(256) void setup_kernel(
    const int* __restrict__ rel,    // [B,P,M,4]
    const int* __restrict__ pinfo,  // [B,N,6]
    float* __restrict__ out,        // mask goes to out[ROWS*FEA + row]
    int* __restrict__ ws)           // [ROWS][8] descriptors
{
    const int row = blockIdx.x * 256 + threadIdx.x;
    if (row >= ROWS) return;
    const int b = row / (P * M);
    const int m = row % M;
    const int branch = m >> 2;

    const int4 sel = *reinterpret_cast<const int4*>(rel + (size_t)row * 4);
    const int zf = (sel.x + sel.y + sel.z + sel.w) > 0;
    const int ia = sel.x;
    const int ib = (branch == 0) ? sel.z : sel.w;
    const int logical = (branch == 2);

    const int* pbase = pinfo + b * N * 6;      // pos[n] = pbase[n*6]
    const int pos_ia = pbase[ia * 6];
    const int pos_ib = pbase[ib * 6];
    const int delta = pos_ia - pos_ib;
    const int u = delta & 511;                  // jnp.mod(delta, 512)
    const int d2 = (u == 0) ? 0 : (32 - __clz(u));
    const int idx = (delta < 0) ? (10 - d2) : (10 + d2);

    const int s0 = pbase[sel.x * 6];
    const int s2 = pbase[sel.z * 6];
    const int s1 = logical ? pbase[sel.y * 6] : 0;
    const int s3 = logical ? pbase[sel.w * 6] : 0;

    int4 da, db;
    da.x = (b * N + ia) * D;                    // gf elem offset A
    da.y = (b * N + ib) * D;                    // gf elem offset B
    da.z = idx * 20;                            // emb table elem offset
    da.w = (logical ? 1 : 0) | (zf ? 2 : 0);    // flags
    const int cb = b * L * DC;
    db.x = cb + s0 * DC;
    db.y = cb + s1 * DC;
    db.z = cb + s2 * DC;
    db.w = cb + s3 * DC;

    reinterpret_cast<int4*>(ws)[(size_t)row * 2]     = da;
    reinterpret_cast<int4*>(ws)[(size_t)row * 2 + 1] = db;

    const bool rm = (sel.x > 0) || (sel.y > 0) || (sel.z > 0) || (sel.w > 0);
    out[(size_t)ROWS * FEA + row] = rm ? 1.0f : 0.0f;
}

// ---------------- stream: gather + concat + store ----------------
__global__ __launch_bounds__(256) void stream_kernel(
    const float* __restrict__ gf,   // [B,N,D]
    const float* __restrict__ cf,   // [B,L,DC]
    const float* __restrict__ dw,   // [20,20]
    const float* __restrict__ sw,   // [20,20]
    const int* __restrict__ ws,     // [ROWS][8]
    float* __restrict__ out)        // [ROWS*FEA]
{
    const int lane  = threadIdx.x & 63;
    const int gwave = (blockIdx.x * 256 + threadIdx.x) >> 6;
    const int nwav  = NBLK * 4;

    for (int r = gwave; r < ROWS; r += nwav) {
        const int row = __builtin_amdgcn_readfirstlane(r);  // force uniform → s_load bases

        const int4 da = reinterpret_cast<const int4*>(ws)[(size_t)row * 2];
        const int4 db = reinterpret_cast<const int4*>(ws)[(size_t)row * 2 + 1];
        const bool logical = (da.w & 1);
        const float zf = (da.w & 2) ? 1.0f : 0.0f;

        const f32x4* gA  = reinterpret_cast<const f32x4*>(gf + da.x);
        const f32x4* gB  = reinterpret_cast<const f32x4*>(gf + da.y);
        const f32x4* dwr = reinterpret_cast<const f32x4*>(dw + da.z);
        const f32x4* swr = reinterpret_cast<const f32x4*>(sw + da.z);
        const f32x4* c0  = reinterpret_cast<const f32x4*>(cf + db.x);
        const f32x4* c1  = reinterpret_cast<const f32x4*>(cf + db.y);
        const f32x4* c2  = reinterpret_cast<const f32x4*>(cf + db.z);
        const f32x4* c3  = reinterpret_cast<const f32x4*>(cf + db.w);

        // Issue ALL row loads before any store (max MLP).
        f32x4 v0 = gA[lane];                        // f4[0,64)   rep A
        f32x4 v1 = gB[lane];                        // f4[64,128) rep B
        f32x4 v2, v3, v4 = {0.f, 0.f, 0.f, 0.f};
        // f4[128,192): 5 emb + 5 semb + c0[0..53]
        if (lane < 5)       v2 = dwr[lane];
        else if (lane < 10) v2 = swr[lane - 5];
        else {              v2 = c0[lane - 10]; if (logical) v2 += c1[lane - 10]; }
        // f4[192,256): c0[54..63] + c2[0..53]
        if (lane < 10) {    v3 = c0[54 + lane]; if (logical) v3 += c1[54 + lane]; }
        else {              v3 = c2[lane - 10]; if (logical) v3 += c3[lane - 10]; }
        // f4[256,266): c2[54..63] (lanes 0..9 only)
        if (lane < 10) {    v4 = c2[54 + lane]; if (logical) v4 += c3[54 + lane]; }

        v0 *= zf; v1 *= zf; v2 *= zf; v3 *= zf; v4 *= zf;

        f32x4* orow = reinterpret_cast<f32x4*>(out + (size_t)row * FEA);
        orow[lane]        = v0;
        orow[64 + lane]   = v1;
        orow[128 + lane]  = v2;
        orow[192 + lane]  = v3;
        if (lane < 10) orow[256 + lane] = v4;
    }
}

extern "C" void kernel_launch(void* const* d_in, const int* in_sizes, int n_in,
                              void* d_out, int out_size, void* d_ws, size_t ws_size,
                              hipStream_t stream) {
    const int*   rel   = (const int*)d_in[0];
    const int*   pinfo = (const int*)d_in[1];
    const float* gf    = (const float*)d_in[2];
    const float* cf    = (const float*)d_in[3];
    const float* dw    = (const float*)d_in[4];
    const float* sw    = (const float*)d_in[5];
    float* out = (float*)d_out;
    int*   ws  = (int*)d_ws;

    setup_kernel<<<(ROWS + 255) / 256, 256, 0, stream>>>(rel, pinfo, out, ws);
    stream_kernel<<<NBLK, 256, 0, stream>>>(gf, cf, dw, sw, ws, out);
}